// Round 11
// baseline (419.678 us; speedup 1.0000x reference)
//
#include <hip/hip_runtime.h>

// ---------------------------------------------------------------------------
// Types / helpers
// ---------------------------------------------------------------------------
typedef __attribute__((ext_vector_type(8))) short short8;      // 8 bf16
typedef __attribute__((ext_vector_type(4))) float f32x4;
typedef __attribute__((ext_vector_type(16))) float f32x16;     // 32x32 mfma acc
typedef __attribute__((ext_vector_type(4))) float float4v;
typedef __attribute__((ext_vector_type(4))) unsigned short ushort4v;
typedef __attribute__((ext_vector_type(4))) unsigned int uint4v;
typedef __attribute__((ext_vector_type(2))) unsigned int uint2v;

#define MFMA16(a, b, c) __builtin_amdgcn_mfma_f32_16x16x32_bf16((a), (b), (c), 0, 0, 0)
#define MFMA32(a, b, c) __builtin_amdgcn_mfma_f32_32x32x16_bf16((a), (b), (c), 0, 0, 0)
#define GLOAD_LDS16(g, s)                                                         \
  __builtin_amdgcn_global_load_lds((const __attribute__((address_space(1))) void*)(g), \
                                   (__attribute__((address_space(3))) void*)(s), 16, 0, 0)
#define EXP2(x) __builtin_amdgcn_exp2f(x)

__device__ __forceinline__ unsigned short f2bf(float f) {
  unsigned u = __builtin_bit_cast(unsigned, f);
  u += 0x7fffu + ((u >> 16) & 1u);   // round-to-nearest-even
  return (unsigned short)(u >> 16);
}

__device__ __forceinline__ unsigned cvtpk(float lo, float hi) {
  unsigned r;
  asm("v_cvt_pk_bf16_f32 %0, %1, %2" : "=v"(r) : "v"(lo), "v"(hi));
  return r;
}

// v_permlane32_swap_b32 a, b: a[32:63] <-> b[0:31]
__device__ __forceinline__ void swap32(unsigned& a, unsigned& b) {
  asm volatile("v_permlane32_swap_b32 %0, %1" : "+v"(a), "+v"(b));
}

__device__ __forceinline__ float bflo(unsigned u) {
  return __builtin_bit_cast(float, u << 16);
}
__device__ __forceinline__ float bfhi(unsigned u) {
  return __builtin_bit_cast(float, u & 0xffff0000u);
}
__device__ __forceinline__ float bf2f(unsigned short u) {
  return __builtin_bit_cast(float, (unsigned)u << 16);
}

// ---------------------------------------------------------------------------
// GEMM: C[M][N] = act(A[M][K] @ B[N][K]^T + bias[N]) (+ bf16 residual)
// BMxBN tile (4 waves, 2x2), BK=32, 2-phase dbuf, 1D grid + XCD swizzle.
// AF32/BF32: operand is fp32 in global; converted to bf16 during staging
// (issue loads early -> compute -> cvt_pk + ds_write -> barrier).  Weights
// are single-use per call, so this removes the standalone cvt pass.
// OUTT: also write C^T for cols >= tcol0 (V^T production); those cols are
// then skipped in the OUTB row-major write (V is consumed only transposed).
// ---------------------------------------------------------------------------
template <int BM, int BN, bool AF32, bool BF32, bool RELU, bool RES,
          bool OUTF, bool OUTB, bool OUTT>
__global__ __launch_bounds__(256) void gemm_bt(const void* __restrict__ Av,
                                               const void* __restrict__ Bv,
                                               const float* __restrict__ bias,
                                               const unsigned short* __restrict__ resB,
                                               float* __restrict__ outF,
                                               unsigned short* __restrict__ outB,
                                               unsigned short* __restrict__ outT,
                                               int tcol0, int ldt,
                                               int M, int N, int K) {
  const unsigned short* Ab = (const unsigned short*)Av;
  const float* Af = (const float*)Av;
  const unsigned short* Bb = (const unsigned short*)Bv;
  const float* Bf = (const float*)Bv;
  __shared__ __align__(16) unsigned short As[2][BM * 32];
  __shared__ __align__(16) unsigned short Bs[2][BN * 32];
  constexpr int MI = BM / 32, MJ = BN / 32, CA = BM / 64, CB = BN / 64;
  const int tid = threadIdx.x;
  const int w = tid >> 6, lane = tid & 63;
  const int l15 = lane & 15, l4 = lane >> 4;

  // 1D grid, bijective XCD swizzle (gridDim.x % 8 == 0)
  const int nwg = gridDim.x;
  const int wg = (blockIdx.x & 7) * (nwg >> 3) + (blockIdx.x >> 3);
  const int nbx = N / BN;
  const int rowBase = (wg / nbx) * BM;
  const int colBase = (wg % nbx) * BN;
  const int wm = w >> 1, wn = w & 1;

  f32x4 acc[MI][MJ] = {};
  float fA[CA][8], fB[CB][8];

  // issue: fp32 -> registers, bf16 -> global_load_lds direct
  auto issueA = [&](int buf, int k0) {
#pragma unroll
    for (int i = 0; i < CA; ++i) {
      const int c = i * 256 + tid;
      if constexpr (AF32) {
        const float* src = Af + (size_t)(rowBase + (c >> 2)) * K + k0 + ((c & 3) << 3);
        *(float4v*)(&fA[i][0]) = *(const float4v*)src;
        *(float4v*)(&fA[i][4]) = *(const float4v*)(src + 4);
      } else {
        GLOAD_LDS16(Ab + (size_t)(rowBase + (c >> 2)) * K + k0 + ((c & 3) << 3),
                    As[buf] + i * 2048 + w * 512);
      }
    }
  };
  auto issueB = [&](int buf, int k0) {
#pragma unroll
    for (int i = 0; i < CB; ++i) {
      const int c = i * 256 + tid;
      if constexpr (BF32) {
        const float* src = Bf + (size_t)(colBase + (c >> 2)) * K + k0 + ((c & 3) << 3);
        *(float4v*)(&fB[i][0]) = *(const float4v*)src;
        *(float4v*)(&fB[i][4]) = *(const float4v*)(src + 4);
      } else {
        GLOAD_LDS16(Bb + (size_t)(colBase + (c >> 2)) * K + k0 + ((c & 3) << 3),
                    Bs[buf] + i * 2048 + w * 512);
      }
    }
  };
  auto writeA = [&](int buf) {
    if constexpr (AF32) {
#pragma unroll
      for (int i = 0; i < CA; ++i) {
        const int c = i * 256 + tid;
        uint4v u = {cvtpk(fA[i][0], fA[i][1]), cvtpk(fA[i][2], fA[i][3]),
                    cvtpk(fA[i][4], fA[i][5]), cvtpk(fA[i][6], fA[i][7])};
        *(uint4v*)(As[buf] + (size_t)c * 8) = u;
      }
    }
  };
  auto writeB = [&](int buf) {
    if constexpr (BF32) {
#pragma unroll
      for (int i = 0; i < CB; ++i) {
        const int c = i * 256 + tid;
        uint4v u = {cvtpk(fB[i][0], fB[i][1]), cvtpk(fB[i][2], fB[i][3]),
                    cvtpk(fB[i][4], fB[i][5]), cvtpk(fB[i][6], fB[i][7])};
        *(uint4v*)(Bs[buf] + (size_t)c * 8) = u;
      }
    }
  };

  issueA(0, 0);
  issueB(0, 0);
  writeA(0);
  writeB(0);
  __syncthreads();

  int p = 0;
  for (int k0 = 0; k0 < K; k0 += 32) {
    const bool more = k0 + 32 < K;
    if (more) {   // issue next tile early (T14)
      issueA(p ^ 1, k0 + 32);
      issueB(p ^ 1, k0 + 32);
    }

    short8 af[MI], bf[MJ];
#pragma unroll
    for (int f = 0; f < MI; ++f)
      af[f] = *(const short8*)(As[p] + (wm * (BM / 2) + f * 16 + l15) * 32 + l4 * 8);
#pragma unroll
    for (int f = 0; f < MJ; ++f)
      bf[f] = *(const short8*)(Bs[p] + (wn * (BN / 2) + f * 16 + l15) * 32 + l4 * 8);
#pragma unroll
    for (int i = 0; i < MI; ++i)
#pragma unroll
      for (int j = 0; j < MJ; ++j)
        acc[i][j] = MFMA16(af[i], bf[j], acc[i][j]);

    if (more) {   // write converted fp32 operands late
      writeA(p ^ 1);
      writeB(p ^ 1);
    }
    __syncthreads();
    p ^= 1;
  }

#pragma unroll
  for (int i = 0; i < MI; ++i) {
    const int row0 = rowBase + wm * (BM / 2) + i * 16 + l4 * 4;
#pragma unroll
    for (int j = 0; j < MJ; ++j) {
      const int col = colBase + wn * (BN / 2) + j * 16 + l15;
      const float bv = bias[col];
      float vv[4];
#pragma unroll
      for (int e = 0; e < 4; ++e) {
        float v = acc[i][j][e] + bv;
        if constexpr (RELU) v = fmaxf(v, 0.f);
        if constexpr (RES) v += bf2f(resB[(size_t)(row0 + e) * N + col]);
        vv[e] = v;
        if constexpr (OUTF) outF[(size_t)(row0 + e) * N + col] = v;
        if constexpr (OUTB) {
          if (!OUTT || col < tcol0) outB[(size_t)(row0 + e) * N + col] = f2bf(v);
        }
      }
      if constexpr (OUTT) {
        if (col >= tcol0) {
          ushort4v t;
          t.x = f2bf(vv[0]); t.y = f2bf(vv[1]); t.z = f2bf(vv[2]); t.w = f2bf(vv[3]);
          *(ushort4v*)(outT + (size_t)(col - tcol0) * ldt + row0) = t;
        }
      }
    }
  }
}

// ---------------------------------------------------------------------------
// Flash attention v4: 32x32x16 MFMA, in-register softmax + P (cvt_pk +
// permlane32_swap), XOR-swizzled [64][64] K/Vt LDS tiles, dbuf staging,
// KSPLIT=4 over keys.  Partials stored bf16.  Combine is a separate kernel
// (R7: fused combine w/ device fences = 15x regression, cross-XCD L2 flush;
//  R9: 16-wave monolithic block = 5x regression, 1 block/CU barrier stalls).
// ---------------------------------------------------------------------------
__global__ __launch_bounds__(256, 4) void flash_attn4(const unsigned short* __restrict__ qkv,
                                                      const unsigned short* __restrict__ vt,
                                                      unsigned short* __restrict__ Op0,
                                                      unsigned short* __restrict__ OpR,
                                                      float* __restrict__ Ml,
                                                      float* __restrict__ Ll,
                                                      int Nseq) {
  __shared__ __align__(16) unsigned short Ks[2][64 * 64];
  __shared__ __align__(16) unsigned short Vs[2][64 * 64];
  const int tid = threadIdx.x, w = tid >> 6, lane = tid & 63;
  const int l31 = lane & 31, l2h = lane >> 5, l7 = l31 & 7;
  const float CSC = 0.18033688011112042f;   // 0.125 * log2(e)

  const int b = blockIdx.x;
  const int head = (b & 7) * 2 + ((b >> 3) & 1);
  const int s = (b >> 4) & 3;
  const int qb = b >> 6;
  const int q0w = qb * 128 + w * 32;

  const unsigned short* Qp = qkv + head * 64;
  const unsigned short* Kp = qkv + 1024 + head * 64;
  const unsigned short* Vtp = vt + (size_t)head * 64 * Nseq;

  short8 qf[4];
#pragma unroll
  for (int ka = 0; ka < 4; ++ka)
    qf[ka] = *(const short8*)(Qp + (size_t)(q0w + l31) * 3072 + ka * 16 + l2h * 8);

  f32x16 OT0 = {}, OT1 = {};
  float m = -1e30f, ls = 0.f;

  const int sr = tid >> 3, su = tid & 7;
  const int sOffA = sr * 64 + ((su ^ (sr & 7)) * 8);
  const int sOffB = sOffA + 32 * 64;

  const int kt0 = s * (Nseq >> 2);
  const int NIT = Nseq >> 8;

  short8 k0 = *(const short8*)(Kp + (size_t)(kt0 + sr) * 3072 + su * 8);
  short8 k1 = *(const short8*)(Kp + (size_t)(kt0 + sr + 32) * 3072 + su * 8);
  short8 v0 = *(const short8*)(Vtp + (size_t)sr * Nseq + kt0 + su * 8);
  short8 v1 = *(const short8*)(Vtp + (size_t)(sr + 32) * Nseq + kt0 + su * 8);
  *(short8*)(Ks[0] + sOffA) = k0;
  *(short8*)(Ks[0] + sOffB) = k1;
  *(short8*)(Vs[0] + sOffA) = v0;
  *(short8*)(Vs[0] + sOffB) = v1;
  __syncthreads();

  int p = 0;
  for (int it = 0; it < NIT; ++it) {
    const bool more = (it + 1) < NIT;
    if (more) {   // issue next-tile loads early (T14)
      const int ktn = kt0 + (it + 1) * 64;
      k0 = *(const short8*)(Kp + (size_t)(ktn + sr) * 3072 + su * 8);
      k1 = *(const short8*)(Kp + (size_t)(ktn + sr + 32) * 3072 + su * 8);
      v0 = *(const short8*)(Vtp + (size_t)sr * Nseq + ktn + su * 8);
      v1 = *(const short8*)(Vtp + (size_t)(sr + 32) * Nseq + ktn + su * 8);
    }
    const unsigned short* KS = Ks[p];
    const unsigned short* VS = Vs[p];

    // ---- QK^T: S^T[key][q]
    f32x16 S0 = {}, S1 = {};
    __builtin_amdgcn_s_setprio(1);
#pragma unroll
    for (int ka = 0; ka < 4; ++ka) {
      const int un = ((ka * 2 + l2h) ^ l7) * 8;
      const short8 a0 = *(const short8*)(KS + l31 * 64 + un);
      const short8 a1 = *(const short8*)(KS + (32 + l31) * 64 + un);
      S0 = MFMA32(a0, qf[ka], S0);
      S1 = MFMA32(a1, qf[ka], S1);
    }
    __builtin_amdgcn_s_setprio(0);

    // ---- row max
    float pm = S0[0];
#pragma unroll
    for (int r = 1; r < 16; ++r) pm = fmaxf(pm, S0[r]);
#pragma unroll
    for (int r = 0; r < 16; ++r) pm = fmaxf(pm, S1[r]);
    pm = fmaxf(pm, __shfl_xor(pm, 32));
    pm *= CSC;

    // defer-max rescale
    if (__any(pm > m + 8.f)) {
      const float mn = fmaxf(m, pm);
      const float fac = EXP2(m - mn);
      m = mn;
      ls *= fac;
#pragma unroll
      for (int r = 0; r < 16; ++r) { OT0[r] *= fac; OT1[r] *= fac; }
    }

    // ---- P = exp2(S*CSC - m)
    float rs = 0.f;
    unsigned W0[4][2], W1[4][2];
#pragma unroll
    for (int g = 0; g < 4; ++g) {
      const float a0 = EXP2(fmaf(S0[4 * g + 0], CSC, -m));
      const float a1 = EXP2(fmaf(S0[4 * g + 1], CSC, -m));
      const float a2 = EXP2(fmaf(S0[4 * g + 2], CSC, -m));
      const float a3 = EXP2(fmaf(S0[4 * g + 3], CSC, -m));
      const float b0 = EXP2(fmaf(S1[4 * g + 0], CSC, -m));
      const float b1 = EXP2(fmaf(S1[4 * g + 1], CSC, -m));
      const float b2 = EXP2(fmaf(S1[4 * g + 2], CSC, -m));
      const float b3 = EXP2(fmaf(S1[4 * g + 3], CSC, -m));
      rs += ((a0 + a1) + (a2 + a3)) + ((b0 + b1) + (b2 + b3));
      W0[g][0] = cvtpk(a0, a1); W0[g][1] = cvtpk(a2, a3);
      W1[g][0] = cvtpk(b0, b1); W1[g][1] = cvtpk(b2, b3);
    }
    rs += __shfl_xor(rs, 32);
    ls += rs;

    // ---- exchange halves -> PV B-frags
    short8 pf[2][2];
#pragma unroll
    for (int ka = 0; ka < 2; ++ka) {
      {
        unsigned x0 = W0[2 * ka][0], y0 = W0[2 * ka + 1][0];
        unsigned x1 = W0[2 * ka][1], y1 = W0[2 * ka + 1][1];
        swap32(x0, y0);
        swap32(x1, y1);
        uint4v u = {x0, x1, y0, y1};
        pf[0][ka] = __builtin_bit_cast(short8, u);
      }
      {
        unsigned x0 = W1[2 * ka][0], y0 = W1[2 * ka + 1][0];
        unsigned x1 = W1[2 * ka][1], y1 = W1[2 * ka + 1][1];
        swap32(x0, y0);
        swap32(x1, y1);
        uint4v u = {x0, x1, y0, y1};
        pf[1][ka] = __builtin_bit_cast(short8, u);
      }
    }

    // ---- O^T += V^T x P^T
    __builtin_amdgcn_s_setprio(1);
#pragma unroll
    for (int sub = 0; sub < 2; ++sub)
#pragma unroll
      for (int ka = 0; ka < 2; ++ka) {
        const int un = ((sub * 4 + ka * 2 + l2h) ^ l7) * 8;
        const short8 va0 = *(const short8*)(VS + l31 * 64 + un);
        const short8 va1 = *(const short8*)(VS + (32 + l31) * 64 + un);
        OT0 = MFMA32(va0, pf[sub][ka], OT0);
        OT1 = MFMA32(va1, pf[sub][ka], OT1);
      }
    __builtin_amdgcn_s_setprio(0);

    if (more) {
      unsigned short* Kn = Ks[p ^ 1];
      unsigned short* Vn = Vs[p ^ 1];
      *(short8*)(Kn + sOffA) = k0;
      *(short8*)(Kn + sOffB) = k1;
      *(short8*)(Vn + sOffA) = v0;
      *(short8*)(Vn + sOffB) = v1;
    }
    __syncthreads();
    p ^= 1;
  }

  // ---- epilogue: bf16 un-normalized partials + (m, ls)
  unsigned short* Ob = (s == 0) ? Op0 : (OpR + (size_t)(s - 1) * Nseq * 1024);
  const int q = q0w + l31;
#pragma unroll
  for (int g = 0; g < 4; ++g) {
    const int d0 = 8 * g + 4 * l2h;
    uint2v t0 = {cvtpk(OT0[4 * g], OT0[4 * g + 1]), cvtpk(OT0[4 * g + 2], OT0[4 * g + 3])};
    uint2v t1 = {cvtpk(OT1[4 * g], OT1[4 * g + 1]), cvtpk(OT1[4 * g + 2], OT1[4 * g + 3])};
    *(uint2v*)(Ob + (size_t)q * 1024 + head * 64 + d0) = t0;
    *(uint2v*)(Ob + (size_t)q * 1024 + head * 64 + 32 + d0) = t1;
  }
  if (l2h == 0) {
    Ml[(size_t)(s * 16 + head) * Nseq + q] = m;
    Ll[(size_t)(s * 16 + head) * Nseq + q] = ls;
  }
}

// ---------------------------------------------------------------------------
// Combine the 4 key-split bf16 partials (exp2 domain) -> bf16 attention out.
// 8 elems/thread, grid 1024.
// ---------------------------------------------------------------------------
__global__ __launch_bounds__(256) void attn_combine4(const unsigned short* __restrict__ Op0,
                                                     const unsigned short* __restrict__ OpR,
                                                     const float* __restrict__ Ml,
                                                     const float* __restrict__ Ll,
                                                     unsigned short* __restrict__ out, int Nseq) {
  const int t = blockIdx.x * 256 + threadIdx.x;
  const int q = t >> 7, c8 = (t & 127) * 8;
  const int head = c8 >> 6;
  float mm[4], lv[4];
  float M = -1e30f;
#pragma unroll
  for (int s = 0; s < 4; ++s) {
    mm[s] = Ml[(size_t)(s * 16 + head) * Nseq + q];
    lv[s] = Ll[(size_t)(s * 16 + head) * Nseq + q];
    M = fmaxf(M, mm[s]);
  }
  float denom = 0.f;
  float acc[8] = {};
#pragma unroll
  for (int s = 0; s < 4; ++s) {
    const float ww = EXP2(mm[s] - M);
    denom += lv[s] * ww;
    const unsigned short* Ob = (s == 0) ? Op0 : (OpR + (size_t)(s - 1) * Nseq * 1024);
    uint4v o = *(const uint4v*)(Ob + (size_t)q * 1024 + c8);
    acc[0] += bflo(o.x) * ww; acc[1] += bfhi(o.x) * ww;
    acc[2] += bflo(o.y) * ww; acc[3] += bfhi(o.y) * ww;
    acc[4] += bflo(o.z) * ww; acc[5] += bfhi(o.z) * ww;
    acc[6] += bflo(o.w) * ww; acc[7] += bfhi(o.w) * ww;
  }
  const float inv = 1.f / denom;
  uint4v r;
  r.x = cvtpk(acc[0] * inv, acc[1] * inv);
  r.y = cvtpk(acc[2] * inv, acc[3] * inv);
  r.z = cvtpk(acc[4] * inv, acc[5] * inv);
  r.w = cvtpk(acc[6] * inv, acc[7] * inv);
  *(uint4v*)(out + (size_t)q * 1024 + c8) = r;
}

// ---------------------------------------------------------------------------
// Row LayerNorm (two-pass, fp32).  One block (256 thr) per row.
// D==1024: float4-vectorized loads/stores.
// ---------------------------------------------------------------------------
template <int D, bool WF, bool WB>
__global__ __launch_bounds__(256) void ln_rows(const float* __restrict__ src,
                                               const float* __restrict__ gw,
                                               const float* __restrict__ bw,
                                               float* __restrict__ outF,
                                               unsigned short* __restrict__ outB) {
  __shared__ float red[4];
  const int row = blockIdx.x;
  const int tid = threadIdx.x, w = tid >> 6;
  const float* r = src + (size_t)row * D;
  if constexpr (D == 1024) {
    float4v v = ((const float4v*)r)[tid];
    float s = (v.x + v.y) + (v.z + v.w);
#pragma unroll
    for (int off = 32; off; off >>= 1) s += __shfl_down(s, off);
    if ((tid & 63) == 0) red[w] = s;
    __syncthreads();
    const float mean = (red[0] + red[1] + red[2] + red[3]) / D;
    __syncthreads();
    const float dx = v.x - mean, dy = v.y - mean, dz = v.z - mean, dw = v.w - mean;
    float q = (dx * dx + dy * dy) + (dz * dz + dw * dw);
#pragma unroll
    for (int off = 32; off; off >>= 1) q += __shfl_down(q, off);
    if ((tid & 63) == 0) red[w] = q;
    __syncthreads();
    const float rstd = rsqrtf((red[0] + red[1] + red[2] + red[3]) / D + 1e-5f);
    float4v g4 = ((const float4v*)gw)[tid];
    float4v b4 = ((const float4v*)bw)[tid];
    float4v o;
    o.x = dx * rstd * g4.x + b4.x;
    o.y = dy * rstd * g4.y + b4.y;
    o.z = dz * rstd * g4.z + b4.z;
    o.w = dw * rstd * g4.w + b4.w;
    if constexpr (WF) ((float4v*)(outF + (size_t)row * D))[tid] = o;
    if constexpr (WB) {
      uint2v u = {cvtpk(o.x, o.y), cvtpk(o.z, o.w)};
      *(uint2v*)(outB + (size_t)row * D + tid * 4) = u;
    }
  } else {
    float v = r[tid];
    float s = v;
#pragma unroll
    for (int off = 32; off; off >>= 1) s += __shfl_down(s, off);
    if ((tid & 63) == 0) red[w] = s;
    __syncthreads();
    const float mean = (red[0] + red[1] + red[2] + red[3]) / D;
    __syncthreads();
    const float d = v - mean;
    float q = d * d;
#pragma unroll
    for (int off = 32; off; off >>= 1) q += __shfl_down(q, off);
    if ((tid & 63) == 0) red[w] = q;
    __syncthreads();
    const float rstd = rsqrtf((red[0] + red[1] + red[2] + red[3]) / D + 1e-5f);
    const float o = d * rstd * gw[tid] + bw[tid];
    if constexpr (WF) outF[(size_t)row * D + tid] = o;
    if constexpr (WB) outB[(size_t)row * D + tid] = f2bf(o);
  }
}

// ---------------------------------------------------------------------------
// Orchestration
// ---------------------------------------------------------------------------
extern "C" void kernel_launch(void* const* d_in, const int* in_sizes, int n_in,
                              void* d_out, int out_size, void* d_ws, size_t ws_size,
                              hipStream_t stream) {
  const int N = 2048, D_IN = 512, H = 1024, D_OUT = 256, NL = 4;
  const float* x    = (const float*)d_in[0];
  const float* W1   = (const float*)d_in[1];
  const float* b1   = (const float*)d_in[2];
  const float* Wqkv = (const float*)d_in[3];
  const float* bqkv = (const float*)d_in[4];
  const float* Wo   = (const float*)d_in[5];
  const float* bo   = (const float*)d_in[6];
  const float* lng  = (const float*)d_in[7];
  const float* lnb  = (const float*)d_in[8];
  const float* W2   = (const float*)d_in[9];
  const float* b2   = (const float*)d_in[10];
  const float* gout = (const float*)d_in[11];
  const float* bout = (const float*)d_in[12];
  float* out = (float*)d_out;

  char* ws = (char*)d_ws;
  auto alloc = [&](size_t bytes) -> char* {
    char* p = ws;
    ws += (bytes + 255) & ~(size_t)255;
    return p;
  };
  unsigned short* hb    = (unsigned short*)alloc((size_t)N * H * 2);
  unsigned short* qkvb  = (unsigned short*)alloc((size_t)N * 3 * H * 2);
  unsigned short* aob   = (unsigned short*)alloc((size_t)N * H * 2);
  unsigned short* vtg   = (unsigned short*)alloc((size_t)H * N * 2);
  unsigned short* opb0  = (unsigned short*)alloc((size_t)N * H * 2);
  unsigned short* opbR  = (unsigned short*)alloc((size_t)3 * N * H * 2);
  float* af  = (float*)alloc((size_t)N * H * 4);
  float* ml  = (float*)alloc((size_t)4 * 16 * N * 4);
  float* ll  = (float*)alloc((size_t)4 * 16 * N * 4);
  float* yf  = (float*)alloc((size_t)N * D_OUT * 4);

  // FC1: h = relu(x @ W1^T + b1) -> hb   (A and B fp32, converted in staging)
  gemm_bt<64, 64, true, true, true, false, false, true, false>
      <<<(N / 64) * (H / 64), 256, 0, stream>>>(
      x, W1, b1, nullptr, nullptr, hb, nullptr, 0, 0, N, H, D_IN);

  for (int l = 0; l < NL; ++l) {
    // qkv = h @ Wqkv^T + bqkv ; V^T into vtg; row-major qkvb only for Q,K
    gemm_bt<128, 128, false, true, false, false, false, true, true>
        <<<(N / 128) * (3 * H / 128), 256, 0, stream>>>(
        hb, Wqkv + (size_t)l * 3 * H * H, bqkv + (size_t)l * 3 * H, nullptr, nullptr, qkvb,
        vtg, 2 * H, N, N, 3 * H, H);
    // flash attention -> bf16 partials
    flash_attn4<<<1024, 256, 0, stream>>>(qkvb, vtg, opb0, opbR, ml, ll, N);
    attn_combine4<<<1024, 256, 0, stream>>>(opb0, opbR, ml, ll, aob, N);
    // o-proj + bf16 residual -> af (fp32)
    gemm_bt<64, 64, false, true, false, true, true, false, false>
        <<<(N / 64) * (H / 64), 256, 0, stream>>>(
        aob, Wo + (size_t)l * H * H, bo + (size_t)l * H, hb, af, nullptr, nullptr, 0, 0,
        N, H, H);
    // h = LN(af) -> hb only
    ln_rows<1024, false, true><<<N, 256, 0, stream>>>(af, lng + (size_t)l * H,
                                                      lnb + (size_t)l * H, nullptr, hb);
  }

  // FC2
  gemm_bt<64, 64, false, true, true, false, true, false, false>
      <<<(N / 64) * (D_OUT / 64), 256, 0, stream>>>(
      hb, W2, b2, nullptr, yf, nullptr, nullptr, 0, 0, N, D_OUT, H);
  ln_rows<256, true, false><<<N, 256, 0, stream>>>(yf, gout, bout, out, nullptr);
}

// Round 12
// 374.045 us; speedup vs baseline: 1.1220x; 1.1220x over previous
//
#include <hip/hip_runtime.h>

// ---------------------------------------------------------------------------
// Types / helpers
// ---------------------------------------------------------------------------
typedef __attribute__((ext_vector_type(8))) short short8;      // 8 bf16
typedef __attribute__((ext_vector_type(4))) float f32x4;
typedef __attribute__((ext_vector_type(16))) float f32x16;     // 32x32 mfma acc
typedef __attribute__((ext_vector_type(4))) float float4v;
typedef __attribute__((ext_vector_type(4))) unsigned short ushort4v;
typedef __attribute__((ext_vector_type(4))) unsigned int uint4v;
typedef __attribute__((ext_vector_type(2))) unsigned int uint2v;

#define MFMA16(a, b, c) __builtin_amdgcn_mfma_f32_16x16x32_bf16((a), (b), (c), 0, 0, 0)
#define MFMA32(a, b, c) __builtin_amdgcn_mfma_f32_32x32x16_bf16((a), (b), (c), 0, 0, 0)
#define GLOAD_LDS16(g, s)                                                         \
  __builtin_amdgcn_global_load_lds((const __attribute__((address_space(1))) void*)(g), \
                                   (__attribute__((address_space(3))) void*)(s), 16, 0, 0)
#define EXP2(x) __builtin_amdgcn_exp2f(x)

__device__ __forceinline__ unsigned short f2bf(float f) {
  unsigned u = __builtin_bit_cast(unsigned, f);
  u += 0x7fffu + ((u >> 16) & 1u);   // round-to-nearest-even
  return (unsigned short)(u >> 16);
}

__device__ __forceinline__ unsigned cvtpk(float lo, float hi) {
  unsigned r;
  asm("v_cvt_pk_bf16_f32 %0, %1, %2" : "=v"(r) : "v"(lo), "v"(hi));
  return r;
}

// v_permlane32_swap_b32 a, b: a[32:63] <-> b[0:31]
__device__ __forceinline__ void swap32(unsigned& a, unsigned& b) {
  asm volatile("v_permlane32_swap_b32 %0, %1" : "+v"(a), "+v"(b));
}

__device__ __forceinline__ float bflo(unsigned u) {
  return __builtin_bit_cast(float, u << 16);
}
__device__ __forceinline__ float bfhi(unsigned u) {
  return __builtin_bit_cast(float, u & 0xffff0000u);
}
__device__ __forceinline__ float bf2f(unsigned short u) {
  return __builtin_bit_cast(float, (unsigned)u << 16);
}

// ---------------------------------------------------------------------------
// Fused fp32 -> bf16 convert for all 5 weight/input arrays (1 launch).
// Weights are re-read ~16x by GEMM row-tiles (R11 lesson: folding the cvt
// into GEMM staging doubles every panel re-read -> +16us/qkv GEMM).
// ---------------------------------------------------------------------------
struct CvtArgs {
  const float* s[5];
  unsigned short* d[5];
  int off[6];
};

__global__ __launch_bounds__(256) void cvt_multi(CvtArgs a, int ntot4) {
  int i4 = blockIdx.x * 256 + threadIdx.x;
  const int stride = gridDim.x * 256;
  for (; i4 < ntot4; i4 += stride) {
    const int idx = i4 * 4;
    int s = 0;
#pragma unroll
    for (int k = 0; k < 4; ++k) s += (idx >= a.off[k + 1]) ? 1 : 0;
    const int local = idx - a.off[s];
    float4v v = *(const float4v*)(a.s[s] + local);
    ushort4v o;
    o.x = f2bf(v.x); o.y = f2bf(v.y); o.z = f2bf(v.z); o.w = f2bf(v.w);
    *(ushort4v*)(a.d[s] + local) = o;
  }
}

// ---------------------------------------------------------------------------
// GEMM: C[M][N] = act(A[M][K] @ B[N][K]^T + bias[N]) (+ bf16 residual)
// BMxBN tile (4 waves, 2x2), BK=32, 2-phase dbuf, 1D grid + XCD swizzle.
// OUTT: also write C^T for cols >= tcol0 (V^T production); those cols are
// skipped in the OUTB row-major write (V is consumed only transposed).
// ---------------------------------------------------------------------------
template <int BM, int BN, bool RELU, bool RES, bool OUTF, bool OUTB, bool OUTT>
__global__ __launch_bounds__(256) void gemm_bt(const unsigned short* __restrict__ A,
                                               const unsigned short* __restrict__ B,
                                               const float* __restrict__ bias,
                                               const unsigned short* __restrict__ resB,
                                               float* __restrict__ outF,
                                               unsigned short* __restrict__ outB,
                                               unsigned short* __restrict__ outT,
                                               int tcol0, int ldt,
                                               int M, int N, int K) {
  __shared__ __align__(16) unsigned short As[2][BM * 32];
  __shared__ __align__(16) unsigned short Bs[2][BN * 32];
  constexpr int MI = BM / 32, MJ = BN / 32, CA = BM / 64, CB = BN / 64;
  const int tid = threadIdx.x;
  const int w = tid >> 6, lane = tid & 63;
  const int l15 = lane & 15, l4 = lane >> 4;

  // 1D grid, bijective XCD swizzle (gridDim.x % 8 == 0)
  const int nwg = gridDim.x;
  const int wg = (blockIdx.x & 7) * (nwg >> 3) + (blockIdx.x >> 3);
  const int nbx = N / BN;
  const int rowBase = (wg / nbx) * BM;
  const int colBase = (wg % nbx) * BN;
  const int wm = w >> 1, wn = w & 1;

  f32x4 acc[MI][MJ] = {};

  auto stage = [&](int buf, int k0) {
#pragma unroll
    for (int i = 0; i < CA; ++i) {
      const int c = i * 256 + tid;
      GLOAD_LDS16(A + (size_t)(rowBase + (c >> 2)) * K + k0 + ((c & 3) << 3),
                  As[buf] + i * 2048 + w * 512);
    }
#pragma unroll
    for (int i = 0; i < CB; ++i) {
      const int c = i * 256 + tid;
      GLOAD_LDS16(B + (size_t)(colBase + (c >> 2)) * K + k0 + ((c & 3) << 3),
                  Bs[buf] + i * 2048 + w * 512);
    }
  };

  stage(0, 0);
  __syncthreads();

  int p = 0;
  for (int k0 = 0; k0 < K; k0 += 32) {
    if (k0 + 32 < K) stage(p ^ 1, k0 + 32);   // issue next tile early

    short8 af[MI], bf[MJ];
#pragma unroll
    for (int f = 0; f < MI; ++f)
      af[f] = *(const short8*)(As[p] + (wm * (BM / 2) + f * 16 + l15) * 32 + l4 * 8);
#pragma unroll
    for (int f = 0; f < MJ; ++f)
      bf[f] = *(const short8*)(Bs[p] + (wn * (BN / 2) + f * 16 + l15) * 32 + l4 * 8);
#pragma unroll
    for (int i = 0; i < MI; ++i)
#pragma unroll
      for (int j = 0; j < MJ; ++j)
        acc[i][j] = MFMA16(af[i], bf[j], acc[i][j]);

    __syncthreads();
    p ^= 1;
  }

#pragma unroll
  for (int i = 0; i < MI; ++i) {
    const int row0 = rowBase + wm * (BM / 2) + i * 16 + l4 * 4;
#pragma unroll
    for (int j = 0; j < MJ; ++j) {
      const int col = colBase + wn * (BN / 2) + j * 16 + l15;
      const float bv = bias[col];
      float vv[4];
#pragma unroll
      for (int e = 0; e < 4; ++e) {
        float v = acc[i][j][e] + bv;
        if constexpr (RELU) v = fmaxf(v, 0.f);
        if constexpr (RES) v += bf2f(resB[(size_t)(row0 + e) * N + col]);
        vv[e] = v;
        if constexpr (OUTF) outF[(size_t)(row0 + e) * N + col] = v;
        if constexpr (OUTB) {
          if (!OUTT || col < tcol0) outB[(size_t)(row0 + e) * N + col] = f2bf(v);
        }
      }
      if constexpr (OUTT) {
        if (col >= tcol0) {
          ushort4v t;
          t.x = f2bf(vv[0]); t.y = f2bf(vv[1]); t.z = f2bf(vv[2]); t.w = f2bf(vv[3]);
          *(ushort4v*)(outT + (size_t)(col - tcol0) * ldt + row0) = t;
        }
      }
    }
  }
}

// ---------------------------------------------------------------------------
// Flash attention v4: 32x32x16 MFMA, in-register softmax + P (cvt_pk +
// permlane32_swap), XOR-swizzled [64][64] K/Vt LDS tiles, dbuf staging,
// KSPLIT=4 over keys.  Partials stored bf16.  Combine is a separate kernel
// (R7: fused combine w/ device fences = 15x regression, cross-XCD L2 flush;
//  R9: 16-wave monolithic block = 5x regression, 1 block/CU barrier stalls).
// ---------------------------------------------------------------------------
__global__ __launch_bounds__(256, 4) void flash_attn4(const unsigned short* __restrict__ qkv,
                                                      const unsigned short* __restrict__ vt,
                                                      unsigned short* __restrict__ Op0,
                                                      unsigned short* __restrict__ OpR,
                                                      float* __restrict__ Ml,
                                                      float* __restrict__ Ll,
                                                      int Nseq) {
  __shared__ __align__(16) unsigned short Ks[2][64 * 64];
  __shared__ __align__(16) unsigned short Vs[2][64 * 64];
  const int tid = threadIdx.x, w = tid >> 6, lane = tid & 63;
  const int l31 = lane & 31, l2h = lane >> 5, l7 = l31 & 7;
  const float CSC = 0.18033688011112042f;   // 0.125 * log2(e)

  const int b = blockIdx.x;
  const int head = (b & 7) * 2 + ((b >> 3) & 1);
  const int s = (b >> 4) & 3;
  const int qb = b >> 6;
  const int q0w = qb * 128 + w * 32;

  const unsigned short* Qp = qkv + head * 64;
  const unsigned short* Kp = qkv + 1024 + head * 64;
  const unsigned short* Vtp = vt + (size_t)head * 64 * Nseq;

  short8 qf[4];
#pragma unroll
  for (int ka = 0; ka < 4; ++ka)
    qf[ka] = *(const short8*)(Qp + (size_t)(q0w + l31) * 3072 + ka * 16 + l2h * 8);

  f32x16 OT0 = {}, OT1 = {};
  float m = -1e30f, ls = 0.f;

  const int sr = tid >> 3, su = tid & 7;
  const int sOffA = sr * 64 + ((su ^ (sr & 7)) * 8);
  const int sOffB = sOffA + 32 * 64;

  const int kt0 = s * (Nseq >> 2);
  const int NIT = Nseq >> 8;

  short8 k0 = *(const short8*)(Kp + (size_t)(kt0 + sr) * 3072 + su * 8);
  short8 k1 = *(const short8*)(Kp + (size_t)(kt0 + sr + 32) * 3072 + su * 8);
  short8 v0 = *(const short8*)(Vtp + (size_t)sr * Nseq + kt0 + su * 8);
  short8 v1 = *(const short8*)(Vtp + (size_t)(sr + 32) * Nseq + kt0 + su * 8);
  *(short8*)(Ks[0] + sOffA) = k0;
  *(short8*)(Ks[0] + sOffB) = k1;
  *(short8*)(Vs[0] + sOffA) = v0;
  *(short8*)(Vs[0] + sOffB) = v1;
  __syncthreads();

  int p = 0;
  for (int it = 0; it < NIT; ++it) {
    const bool more = (it + 1) < NIT;
    if (more) {   // issue next-tile loads early (T14)
      const int ktn = kt0 + (it + 1) * 64;
      k0 = *(const short8*)(Kp + (size_t)(ktn + sr) * 3072 + su * 8);
      k1 = *(const short8*)(Kp + (size_t)(ktn + sr + 32) * 3072 + su * 8);
      v0 = *(const short8*)(Vtp + (size_t)sr * Nseq + ktn + su * 8);
      v1 = *(const short8*)(Vtp + (size_t)(sr + 32) * Nseq + ktn + su * 8);
    }
    const unsigned short* KS = Ks[p];
    const unsigned short* VS = Vs[p];

    // ---- QK^T: S^T[key][q]
    f32x16 S0 = {}, S1 = {};
    __builtin_amdgcn_s_setprio(1);
#pragma unroll
    for (int ka = 0; ka < 4; ++ka) {
      const int un = ((ka * 2 + l2h) ^ l7) * 8;
      const short8 a0 = *(const short8*)(KS + l31 * 64 + un);
      const short8 a1 = *(const short8*)(KS + (32 + l31) * 64 + un);
      S0 = MFMA32(a0, qf[ka], S0);
      S1 = MFMA32(a1, qf[ka], S1);
    }
    __builtin_amdgcn_s_setprio(0);

    // ---- row max
    float pm = S0[0];
#pragma unroll
    for (int r = 1; r < 16; ++r) pm = fmaxf(pm, S0[r]);
#pragma unroll
    for (int r = 0; r < 16; ++r) pm = fmaxf(pm, S1[r]);
    pm = fmaxf(pm, __shfl_xor(pm, 32));
    pm *= CSC;

    // defer-max rescale
    if (__any(pm > m + 8.f)) {
      const float mn = fmaxf(m, pm);
      const float fac = EXP2(m - mn);
      m = mn;
      ls *= fac;
#pragma unroll
      for (int r = 0; r < 16; ++r) { OT0[r] *= fac; OT1[r] *= fac; }
    }

    // ---- P = exp2(S*CSC - m)
    float rs = 0.f;
    unsigned W0[4][2], W1[4][2];
#pragma unroll
    for (int g = 0; g < 4; ++g) {
      const float a0 = EXP2(fmaf(S0[4 * g + 0], CSC, -m));
      const float a1 = EXP2(fmaf(S0[4 * g + 1], CSC, -m));
      const float a2 = EXP2(fmaf(S0[4 * g + 2], CSC, -m));
      const float a3 = EXP2(fmaf(S0[4 * g + 3], CSC, -m));
      const float b0 = EXP2(fmaf(S1[4 * g + 0], CSC, -m));
      const float b1 = EXP2(fmaf(S1[4 * g + 1], CSC, -m));
      const float b2 = EXP2(fmaf(S1[4 * g + 2], CSC, -m));
      const float b3 = EXP2(fmaf(S1[4 * g + 3], CSC, -m));
      rs += ((a0 + a1) + (a2 + a3)) + ((b0 + b1) + (b2 + b3));
      W0[g][0] = cvtpk(a0, a1); W0[g][1] = cvtpk(a2, a3);
      W1[g][0] = cvtpk(b0, b1); W1[g][1] = cvtpk(b2, b3);
    }
    rs += __shfl_xor(rs, 32);
    ls += rs;

    // ---- exchange halves -> PV B-frags
    short8 pf[2][2];
#pragma unroll
    for (int ka = 0; ka < 2; ++ka) {
      {
        unsigned x0 = W0[2 * ka][0], y0 = W0[2 * ka + 1][0];
        unsigned x1 = W0[2 * ka][1], y1 = W0[2 * ka + 1][1];
        swap32(x0, y0);
        swap32(x1, y1);
        uint4v u = {x0, x1, y0, y1};
        pf[0][ka] = __builtin_bit_cast(short8, u);
      }
      {
        unsigned x0 = W1[2 * ka][0], y0 = W1[2 * ka + 1][0];
        unsigned x1 = W1[2 * ka][1], y1 = W1[2 * ka + 1][1];
        swap32(x0, y0);
        swap32(x1, y1);
        uint4v u = {x0, x1, y0, y1};
        pf[1][ka] = __builtin_bit_cast(short8, u);
      }
    }

    // ---- O^T += V^T x P^T
    __builtin_amdgcn_s_setprio(1);
#pragma unroll
    for (int sub = 0; sub < 2; ++sub)
#pragma unroll
      for (int ka = 0; ka < 2; ++ka) {
        const int un = ((sub * 4 + ka * 2 + l2h) ^ l7) * 8;
        const short8 va0 = *(const short8*)(VS + l31 * 64 + un);
        const short8 va1 = *(const short8*)(VS + (32 + l31) * 64 + un);
        OT0 = MFMA32(va0, pf[sub][ka], OT0);
        OT1 = MFMA32(va1, pf[sub][ka], OT1);
      }
    __builtin_amdgcn_s_setprio(0);

    if (more) {
      unsigned short* Kn = Ks[p ^ 1];
      unsigned short* Vn = Vs[p ^ 1];
      *(short8*)(Kn + sOffA) = k0;
      *(short8*)(Kn + sOffB) = k1;
      *(short8*)(Vn + sOffA) = v0;
      *(short8*)(Vn + sOffB) = v1;
    }
    __syncthreads();
    p ^= 1;
  }

  // ---- epilogue: bf16 un-normalized partials + (m, ls)
  unsigned short* Ob = (s == 0) ? Op0 : (OpR + (size_t)(s - 1) * Nseq * 1024);
  const int q = q0w + l31;
#pragma unroll
  for (int g = 0; g < 4; ++g) {
    const int d0 = 8 * g + 4 * l2h;
    uint2v t0 = {cvtpk(OT0[4 * g], OT0[4 * g + 1]), cvtpk(OT0[4 * g + 2], OT0[4 * g + 3])};
    uint2v t1 = {cvtpk(OT1[4 * g], OT1[4 * g + 1]), cvtpk(OT1[4 * g + 2], OT1[4 * g + 3])};
    *(uint2v*)(Ob + (size_t)q * 1024 + head * 64 + d0) = t0;
    *(uint2v*)(Ob + (size_t)q * 1024 + head * 64 + 32 + d0) = t1;
  }
  if (l2h == 0) {
    Ml[(size_t)(s * 16 + head) * Nseq + q] = m;
    Ll[(size_t)(s * 16 + head) * Nseq + q] = ls;
  }
}

// ---------------------------------------------------------------------------
// Combine the 4 key-split bf16 partials (exp2 domain) -> bf16 attention out.
// 8 elems/thread, grid 1024.
// ---------------------------------------------------------------------------
__global__ __launch_bounds__(256) void attn_combine4(const unsigned short* __restrict__ Op0,
                                                     const unsigned short* __restrict__ OpR,
                                                     const float* __restrict__ Ml,
                                                     const float* __restrict__ Ll,
                                                     unsigned short* __restrict__ out, int Nseq) {
  const int t = blockIdx.x * 256 + threadIdx.x;
  const int q = t >> 7, c8 = (t & 127) * 8;
  const int head = c8 >> 6;
  float mm[4], lv[4];
  float M = -1e30f;
#pragma unroll
  for (int s = 0; s < 4; ++s) {
    mm[s] = Ml[(size_t)(s * 16 + head) * Nseq + q];
    lv[s] = Ll[(size_t)(s * 16 + head) * Nseq + q];
    M = fmaxf(M, mm[s]);
  }
  float denom = 0.f;
  float acc[8] = {};
#pragma unroll
  for (int s = 0; s < 4; ++s) {
    const float ww = EXP2(mm[s] - M);
    denom += lv[s] * ww;
    const unsigned short* Ob = (s == 0) ? Op0 : (OpR + (size_t)(s - 1) * Nseq * 1024);
    uint4v o = *(const uint4v*)(Ob + (size_t)q * 1024 + c8);
    acc[0] += bflo(o.x) * ww; acc[1] += bfhi(o.x) * ww;
    acc[2] += bflo(o.y) * ww; acc[3] += bfhi(o.y) * ww;
    acc[4] += bflo(o.z) * ww; acc[5] += bfhi(o.z) * ww;
    acc[6] += bflo(o.w) * ww; acc[7] += bfhi(o.w) * ww;
  }
  const float inv = 1.f / denom;
  uint4v r;
  r.x = cvtpk(acc[0] * inv, acc[1] * inv);
  r.y = cvtpk(acc[2] * inv, acc[3] * inv);
  r.z = cvtpk(acc[4] * inv, acc[5] * inv);
  r.w = cvtpk(acc[6] * inv, acc[7] * inv);
  *(uint4v*)(out + (size_t)q * 1024 + c8) = r;
}

// ---------------------------------------------------------------------------
// Row LayerNorm (two-pass, fp32).  One block (256 thr) per row.
// D==1024: float4-vectorized loads/stores.
// ---------------------------------------------------------------------------
template <int D, bool WF, bool WB>
__global__ __launch_bounds__(256) void ln_rows(const float* __restrict__ src,
                                               const float* __restrict__ gw,
                                               const float* __restrict__ bw,
                                               float* __restrict__ outF,
                                               unsigned short* __restrict__ outB) {
  __shared__ float red[4];
  const int row = blockIdx.x;
  const int tid = threadIdx.x, w = tid >> 6;
  const float* r = src + (size_t)row * D;
  if constexpr (D == 1024) {
    float4v v = ((const float4v*)r)[tid];
    float s = (v.x + v.y) + (v.z + v.w);
#pragma unroll
    for (int off = 32; off; off >>= 1) s += __shfl_down(s, off);
    if ((tid & 63) == 0) red[w] = s;
    __syncthreads();
    const float mean = (red[0] + red[1] + red[2] + red[3]) / D;
    __syncthreads();
    const float dx = v.x - mean, dy = v.y - mean, dz = v.z - mean, dw = v.w - mean;
    float q = (dx * dx + dy * dy) + (dz * dz + dw * dw);
#pragma unroll
    for (int off = 32; off; off >>= 1) q += __shfl_down(q, off);
    if ((tid & 63) == 0) red[w] = q;
    __syncthreads();
    const float rstd = rsqrtf((red[0] + red[1] + red[2] + red[3]) / D + 1e-5f);
    float4v g4 = ((const float4v*)gw)[tid];
    float4v b4 = ((const float4v*)bw)[tid];
    float4v o;
    o.x = dx * rstd * g4.x + b4.x;
    o.y = dy * rstd * g4.y + b4.y;
    o.z = dz * rstd * g4.z + b4.z;
    o.w = dw * rstd * g4.w + b4.w;
    if constexpr (WF) ((float4v*)(outF + (size_t)row * D))[tid] = o;
    if constexpr (WB) {
      uint2v u = {cvtpk(o.x, o.y), cvtpk(o.z, o.w)};
      *(uint2v*)(outB + (size_t)row * D + tid * 4) = u;
    }
  } else {
    float v = r[tid];
    float s = v;
#pragma unroll
    for (int off = 32; off; off >>= 1) s += __shfl_down(s, off);
    if ((tid & 63) == 0) red[w] = s;
    __syncthreads();
    const float mean = (red[0] + red[1] + red[2] + red[3]) / D;
    __syncthreads();
    const float d = v - mean;
    float q = d * d;
#pragma unroll
    for (int off = 32; off; off >>= 1) q += __shfl_down(q, off);
    if ((tid & 63) == 0) red[w] = q;
    __syncthreads();
    const float rstd = rsqrtf((red[0] + red[1] + red[2] + red[3]) / D + 1e-5f);
    const float o = d * rstd * gw[tid] + bw[tid];
    if constexpr (WF) outF[(size_t)row * D + tid] = o;
    if constexpr (WB) outB[(size_t)row * D + tid] = f2bf(o);
  }
}

// ---------------------------------------------------------------------------
// Orchestration
// ---------------------------------------------------------------------------
extern "C" void kernel_launch(void* const* d_in, const int* in_sizes, int n_in,
                              void* d_out, int out_size, void* d_ws, size_t ws_size,
                              hipStream_t stream) {
  const int N = 2048, D_IN = 512, H = 1024, D_OUT = 256, NL = 4;
  const float* x    = (const float*)d_in[0];
  const float* W1   = (const float*)d_in[1];
  const float* b1   = (const float*)d_in[2];
  const float* Wqkv = (const float*)d_in[3];
  const float* bqkv = (const float*)d_in[4];
  const float* Wo   = (const float*)d_in[5];
  const float* bo   = (const float*)d_in[6];
  const float* lng  = (const float*)d_in[7];
  const float* lnb  = (const float*)d_in[8];
  const float* W2   = (const float*)d_in[9];
  const float* b2   = (const float*)d_in[10];
  const float* gout = (const float*)d_in[11];
  const float* bout = (const float*)d_in[12];
  float* out = (float*)d_out;

  char* ws = (char*)d_ws;
  auto alloc = [&](size_t bytes) -> char* {
    char* p = ws;
    ws += (bytes + 255) & ~(size_t)255;
    return p;
  };
  unsigned short* xb    = (unsigned short*)alloc((size_t)N * D_IN * 2);
  unsigned short* W1b   = (unsigned short*)alloc((size_t)H * D_IN * 2);
  unsigned short* Wqkvb = (unsigned short*)alloc((size_t)NL * 3 * H * H * 2);
  unsigned short* Wob   = (unsigned short*)alloc((size_t)NL * H * H * 2);
  unsigned short* W2b   = (unsigned short*)alloc((size_t)D_OUT * H * 2);
  unsigned short* hb    = (unsigned short*)alloc((size_t)N * H * 2);
  unsigned short* qkvb  = (unsigned short*)alloc((size_t)N * 3 * H * 2);
  unsigned short* aob   = (unsigned short*)alloc((size_t)N * H * 2);
  unsigned short* vtg   = (unsigned short*)alloc((size_t)H * N * 2);
  unsigned short* opb0  = (unsigned short*)alloc((size_t)N * H * 2);
  unsigned short* opbR  = (unsigned short*)alloc((size_t)3 * N * H * 2);
  float* af  = (float*)alloc((size_t)N * H * 4);
  float* ml  = (float*)alloc((size_t)4 * 16 * N * 4);
  float* ll  = (float*)alloc((size_t)4 * 16 * N * 4);
  float* yf  = (float*)alloc((size_t)N * D_OUT * 4);

  // ---- fused bf16 conversion (1 launch for all 5 arrays)
  CvtArgs ca;
  ca.s[0] = x;    ca.d[0] = xb;
  ca.s[1] = W1;   ca.d[1] = W1b;
  ca.s[2] = Wqkv; ca.d[2] = Wqkvb;
  ca.s[3] = Wo;   ca.d[3] = Wob;
  ca.s[4] = W2;   ca.d[4] = W2b;
  const int n0 = N * D_IN, n1 = H * D_IN, n2 = NL * 3 * H * H, n3 = NL * H * H, n4 = D_OUT * H;
  ca.off[0] = 0;
  ca.off[1] = n0;
  ca.off[2] = n0 + n1;
  ca.off[3] = n0 + n1 + n2;
  ca.off[4] = n0 + n1 + n2 + n3;
  ca.off[5] = n0 + n1 + n2 + n3 + n4;
  const int ntot4 = ca.off[5] / 4;
  cvt_multi<<<2048, 256, 0, stream>>>(ca, ntot4);

  // FC1: h = relu(x @ W1^T + b1) -> hb   (512 blocks, 2/CU)
  gemm_bt<64, 64, true, false, false, true, false><<<(N / 64) * (H / 64), 256, 0, stream>>>(
      xb, W1b, b1, nullptr, nullptr, hb, nullptr, 0, 0, N, H, D_IN);

  for (int l = 0; l < NL; ++l) {
    // qkv = h @ Wqkv^T + bqkv ; V^T into vtg; row-major writes only for Q,K
    gemm_bt<128, 128, false, false, false, true, true><<<(N / 128) * (3 * H / 128), 256, 0, stream>>>(
        hb, Wqkvb + (size_t)l * 3 * H * H, bqkv + (size_t)l * 3 * H, nullptr, nullptr, qkvb,
        vtg, 2 * H, N, N, 3 * H, H);
    // flash attention -> bf16 partials
    flash_attn4<<<1024, 256, 0, stream>>>(qkvb, vtg, opb0, opbR, ml, ll, N);
    attn_combine4<<<1024, 256, 0, stream>>>(opb0, opbR, ml, ll, aob, N);
    // o-proj + bf16 residual -> af (fp32)   (512 blocks, 2/CU)
    gemm_bt<64, 64, false, true, true, false, false><<<(N / 64) * (H / 64), 256, 0, stream>>>(
        aob, Wob + (size_t)l * H * H, bo + (size_t)l * H, hb, af, nullptr, nullptr, 0, 0,
        N, H, H);
    // h = LN(af) -> hb only
    ln_rows<1024, false, true><<<N, 256, 0, stream>>>(af, lng + (size_t)l * H,
                                                      lnb + (size_t)l * H, nullptr, hb);
  }

  // FC2 (128 blocks of 64x64)
  gemm_bt<64, 64, true, false, true, false, false><<<(N / 64) * (D_OUT / 64), 256, 0, stream>>>(
      hb, W2b, b2, nullptr, yf, nullptr, nullptr, 0, 0, N, D_OUT, H);
  ln_rows<256, true, false><<<N, 256, 0, stream>>>(yf, gout, bout, out, nullptr);
}

// Round 13
// 370.081 us; speedup vs baseline: 1.1340x; 1.0107x over previous
//
#include <hip/hip_runtime.h>

// ---------------------------------------------------------------------------
// Types / helpers
// ---------------------------------------------------------------------------
typedef __attribute__((ext_vector_type(8))) short short8;      // 8 bf16
typedef __attribute__((ext_vector_type(4))) float f32x4;
typedef __attribute__((ext_vector_type(16))) float f32x16;     // 32x32 mfma acc
typedef __attribute__((ext_vector_type(4))) float float4v;
typedef __attribute__((ext_vector_type(4))) unsigned short ushort4v;
typedef __attribute__((ext_vector_type(4))) unsigned int uint4v;
typedef __attribute__((ext_vector_type(2))) unsigned int uint2v;

#define MFMA16(a, b, c) __builtin_amdgcn_mfma_f32_16x16x32_bf16((a), (b), (c), 0, 0, 0)
#define MFMA32(a, b, c) __builtin_amdgcn_mfma_f32_32x32x16_bf16((a), (b), (c), 0, 0, 0)
#define GLOAD_LDS16(g, s)                                                         \
  __builtin_amdgcn_global_load_lds((const __attribute__((address_space(1))) void*)(g), \
                                   (__attribute__((address_space(3))) void*)(s), 16, 0, 0)
#define EXP2(x) __builtin_amdgcn_exp2f(x)

__device__ __forceinline__ unsigned short f2bf(float f) {
  unsigned u = __builtin_bit_cast(unsigned, f);
  u += 0x7fffu + ((u >> 16) & 1u);   // round-to-nearest-even
  return (unsigned short)(u >> 16);
}

__device__ __forceinline__ unsigned cvtpk(float lo, float hi) {
  unsigned r;
  asm("v_cvt_pk_bf16_f32 %0, %1, %2" : "=v"(r) : "v"(lo), "v"(hi));
  return r;
}

// v_permlane32_swap_b32 a, b: a[32:63] <-> b[0:31]
__device__ __forceinline__ void swap32(unsigned& a, unsigned& b) {
  asm volatile("v_permlane32_swap_b32 %0, %1" : "+v"(a), "+v"(b));
}

__device__ __forceinline__ float bflo(unsigned u) {
  return __builtin_bit_cast(float, u << 16);
}
__device__ __forceinline__ float bfhi(unsigned u) {
  return __builtin_bit_cast(float, u & 0xffff0000u);
}
__device__ __forceinline__ float bf2f(unsigned short u) {
  return __builtin_bit_cast(float, (unsigned)u << 16);
}

// ---------------------------------------------------------------------------
// Fused fp32 -> bf16 convert for all 5 weight/input arrays (1 launch).
// Weights are re-read ~16-32x by GEMM tiles (R11 lesson: folding the cvt
// into GEMM staging multiplies every panel re-read -> +16us/qkv GEMM).
// ---------------------------------------------------------------------------
struct CvtArgs {
  const float* s[5];
  unsigned short* d[5];
  int off[6];
};

__global__ __launch_bounds__(256) void cvt_multi(CvtArgs a, int ntot4) {
  int i4 = blockIdx.x * 256 + threadIdx.x;
  const int stride = gridDim.x * 256;
  for (; i4 < ntot4; i4 += stride) {
    const int idx = i4 * 4;
    int s = 0;
#pragma unroll
    for (int k = 0; k < 4; ++k) s += (idx >= a.off[k + 1]) ? 1 : 0;
    const int local = idx - a.off[s];
    float4v v = *(const float4v*)(a.s[s] + local);
    ushort4v o;
    o.x = f2bf(v.x); o.y = f2bf(v.y); o.z = f2bf(v.z); o.w = f2bf(v.w);
    *(ushort4v*)(a.d[s] + local) = o;
  }
}

// ---------------------------------------------------------------------------
// GEMM: C[M][N] = act(A[M][K] @ B[N][K]^T + bias[N]) (+ bf16 residual)
// BMxBN tile (4 waves, 2x2), BK=32, 2-phase dbuf, 1D grid + XCD swizzle.
// OUTT: also write C^T for cols >= tcol0 (V^T production); those cols are
// skipped in the OUTB row-major write (V is consumed only transposed).
// ---------------------------------------------------------------------------
template <int BM, int BN, bool RELU, bool RES, bool OUTF, bool OUTB, bool OUTT>
__global__ __launch_bounds__(256) void gemm_bt(const unsigned short* __restrict__ A,
                                               const unsigned short* __restrict__ B,
                                               const float* __restrict__ bias,
                                               const unsigned short* __restrict__ resB,
                                               float* __restrict__ outF,
                                               unsigned short* __restrict__ outB,
                                               unsigned short* __restrict__ outT,
                                               int tcol0, int ldt,
                                               int M, int N, int K) {
  __shared__ __align__(16) unsigned short As[2][BM * 32];
  __shared__ __align__(16) unsigned short Bs[2][BN * 32];
  constexpr int MI = BM / 32, MJ = BN / 32, CA = BM / 64, CB = BN / 64;
  const int tid = threadIdx.x;
  const int w = tid >> 6, lane = tid & 63;
  const int l15 = lane & 15, l4 = lane >> 4;

  // 1D grid, bijective XCD swizzle (gridDim.x % 8 == 0)
  const int nwg = gridDim.x;
  const int wg = (blockIdx.x & 7) * (nwg >> 3) + (blockIdx.x >> 3);
  const int nbx = N / BN;
  const int rowBase = (wg / nbx) * BM;
  const int colBase = (wg % nbx) * BN;
  const int wm = w >> 1, wn = w & 1;

  f32x4 acc[MI][MJ] = {};

  auto stage = [&](int buf, int k0) {
#pragma unroll
    for (int i = 0; i < CA; ++i) {
      const int c = i * 256 + tid;
      GLOAD_LDS16(A + (size_t)(rowBase + (c >> 2)) * K + k0 + ((c & 3) << 3),
                  As[buf] + i * 2048 + w * 512);
    }
#pragma unroll
    for (int i = 0; i < CB; ++i) {
      const int c = i * 256 + tid;
      GLOAD_LDS16(B + (size_t)(colBase + (c >> 2)) * K + k0 + ((c & 3) << 3),
                  Bs[buf] + i * 2048 + w * 512);
    }
  };

  stage(0, 0);
  __syncthreads();

  int p = 0;
  for (int k0 = 0; k0 < K; k0 += 32) {
    if (k0 + 32 < K) stage(p ^ 1, k0 + 32);   // issue next tile early

    short8 af[MI], bf[MJ];
#pragma unroll
    for (int f = 0; f < MI; ++f)
      af[f] = *(const short8*)(As[p] + (wm * (BM / 2) + f * 16 + l15) * 32 + l4 * 8);
#pragma unroll
    for (int f = 0; f < MJ; ++f)
      bf[f] = *(const short8*)(Bs[p] + (wn * (BN / 2) + f * 16 + l15) * 32 + l4 * 8);
#pragma unroll
    for (int i = 0; i < MI; ++i)
#pragma unroll
      for (int j = 0; j < MJ; ++j)
        acc[i][j] = MFMA16(af[i], bf[j], acc[i][j]);

    __syncthreads();
    p ^= 1;
  }

#pragma unroll
  for (int i = 0; i < MI; ++i) {
    const int row0 = rowBase + wm * (BM / 2) + i * 16 + l4 * 4;
#pragma unroll
    for (int j = 0; j < MJ; ++j) {
      const int col = colBase + wn * (BN / 2) + j * 16 + l15;
      const float bv = bias[col];
      float vv[4];
#pragma unroll
      for (int e = 0; e < 4; ++e) {
        float v = acc[i][j][e] + bv;
        if constexpr (RELU) v = fmaxf(v, 0.f);
        if constexpr (RES) v += bf2f(resB[(size_t)(row0 + e) * N + col]);
        vv[e] = v;
        if constexpr (OUTF) outF[(size_t)(row0 + e) * N + col] = v;
        if constexpr (OUTB) {
          if (!OUTT || col < tcol0) outB[(size_t)(row0 + e) * N + col] = f2bf(v);
        }
      }
      if constexpr (OUTT) {
        if (col >= tcol0) {
          ushort4v t;
          t.x = f2bf(vv[0]); t.y = f2bf(vv[1]); t.z = f2bf(vv[2]); t.w = f2bf(vv[3]);
          *(ushort4v*)(outT + (size_t)(col - tcol0) * ldt + row0) = t;
        }
      }
    }
  }
}

// ---------------------------------------------------------------------------
// Flash attention v4: 32x32x16 MFMA, in-register softmax + P (cvt_pk +
// permlane32_swap), XOR-swizzled [64][64] K/Vt LDS tiles, dbuf staging,
// KSPLIT=4 over keys.  Partials stored bf16.  Combine is a separate kernel
// (R7: fused combine w/ device fences = 15x regression, cross-XCD L2 flush;
//  R9: 16-wave monolithic block = 5x regression, 1 block/CU barrier stalls).
// ---------------------------------------------------------------------------
__global__ __launch_bounds__(256, 4) void flash_attn4(const unsigned short* __restrict__ qkv,
                                                      const unsigned short* __restrict__ vt,
                                                      unsigned short* __restrict__ Op0,
                                                      unsigned short* __restrict__ OpR,
                                                      float* __restrict__ Ml,
                                                      float* __restrict__ Ll,
                                                      int Nseq) {
  __shared__ __align__(16) unsigned short Ks[2][64 * 64];
  __shared__ __align__(16) unsigned short Vs[2][64 * 64];
  const int tid = threadIdx.x, w = tid >> 6, lane = tid & 63;
  const int l31 = lane & 31, l2h = lane >> 5, l7 = l31 & 7;
  const float CSC = 0.18033688011112042f;   // 0.125 * log2(e)

  const int b = blockIdx.x;
  const int head = (b & 7) * 2 + ((b >> 3) & 1);
  const int s = (b >> 4) & 3;
  const int qb = b >> 6;
  const int q0w = qb * 128 + w * 32;

  const unsigned short* Qp = qkv + head * 64;
  const unsigned short* Kp = qkv + 1024 + head * 64;
  const unsigned short* Vtp = vt + (size_t)head * 64 * Nseq;

  short8 qf[4];
#pragma unroll
  for (int ka = 0; ka < 4; ++ka)
    qf[ka] = *(const short8*)(Qp + (size_t)(q0w + l31) * 3072 + ka * 16 + l2h * 8);

  f32x16 OT0 = {}, OT1 = {};
  float m = -1e30f, ls = 0.f;

  const int sr = tid >> 3, su = tid & 7;
  const int sOffA = sr * 64 + ((su ^ (sr & 7)) * 8);
  const int sOffB = sOffA + 32 * 64;

  const int kt0 = s * (Nseq >> 2);
  const int NIT = Nseq >> 8;

  short8 k0 = *(const short8*)(Kp + (size_t)(kt0 + sr) * 3072 + su * 8);
  short8 k1 = *(const short8*)(Kp + (size_t)(kt0 + sr + 32) * 3072 + su * 8);
  short8 v0 = *(const short8*)(Vtp + (size_t)sr * Nseq + kt0 + su * 8);
  short8 v1 = *(const short8*)(Vtp + (size_t)(sr + 32) * Nseq + kt0 + su * 8);
  *(short8*)(Ks[0] + sOffA) = k0;
  *(short8*)(Ks[0] + sOffB) = k1;
  *(short8*)(Vs[0] + sOffA) = v0;
  *(short8*)(Vs[0] + sOffB) = v1;
  __syncthreads();

  int p = 0;
  for (int it = 0; it < NIT; ++it) {
    const bool more = (it + 1) < NIT;
    if (more) {   // issue next-tile loads early (T14)
      const int ktn = kt0 + (it + 1) * 64;
      k0 = *(const short8*)(Kp + (size_t)(ktn + sr) * 3072 + su * 8);
      k1 = *(const short8*)(Kp + (size_t)(ktn + sr + 32) * 3072 + su * 8);
      v0 = *(const short8*)(Vtp + (size_t)sr * Nseq + ktn + su * 8);
      v1 = *(const short8*)(Vtp + (size_t)(sr + 32) * Nseq + ktn + su * 8);
    }
    const unsigned short* KS = Ks[p];
    const unsigned short* VS = Vs[p];

    // ---- QK^T: S^T[key][q]
    f32x16 S0 = {}, S1 = {};
    __builtin_amdgcn_s_setprio(1);
#pragma unroll
    for (int ka = 0; ka < 4; ++ka) {
      const int un = ((ka * 2 + l2h) ^ l7) * 8;
      const short8 a0 = *(const short8*)(KS + l31 * 64 + un);
      const short8 a1 = *(const short8*)(KS + (32 + l31) * 64 + un);
      S0 = MFMA32(a0, qf[ka], S0);
      S1 = MFMA32(a1, qf[ka], S1);
    }
    __builtin_amdgcn_s_setprio(0);

    // ---- row max
    float pm = S0[0];
#pragma unroll
    for (int r = 1; r < 16; ++r) pm = fmaxf(pm, S0[r]);
#pragma unroll
    for (int r = 0; r < 16; ++r) pm = fmaxf(pm, S1[r]);
    pm = fmaxf(pm, __shfl_xor(pm, 32));
    pm *= CSC;

    // defer-max rescale
    if (__any(pm > m + 8.f)) {
      const float mn = fmaxf(m, pm);
      const float fac = EXP2(m - mn);
      m = mn;
      ls *= fac;
#pragma unroll
      for (int r = 0; r < 16; ++r) { OT0[r] *= fac; OT1[r] *= fac; }
    }

    // ---- P = exp2(S*CSC - m)
    float rs = 0.f;
    unsigned W0[4][2], W1[4][2];
#pragma unroll
    for (int g = 0; g < 4; ++g) {
      const float a0 = EXP2(fmaf(S0[4 * g + 0], CSC, -m));
      const float a1 = EXP2(fmaf(S0[4 * g + 1], CSC, -m));
      const float a2 = EXP2(fmaf(S0[4 * g + 2], CSC, -m));
      const float a3 = EXP2(fmaf(S0[4 * g + 3], CSC, -m));
      const float b0 = EXP2(fmaf(S1[4 * g + 0], CSC, -m));
      const float b1 = EXP2(fmaf(S1[4 * g + 1], CSC, -m));
      const float b2 = EXP2(fmaf(S1[4 * g + 2], CSC, -m));
      const float b3 = EXP2(fmaf(S1[4 * g + 3], CSC, -m));
      rs += ((a0 + a1) + (a2 + a3)) + ((b0 + b1) + (b2 + b3));
      W0[g][0] = cvtpk(a0, a1); W0[g][1] = cvtpk(a2, a3);
      W1[g][0] = cvtpk(b0, b1); W1[g][1] = cvtpk(b2, b3);
    }
    rs += __shfl_xor(rs, 32);
    ls += rs;

    // ---- exchange halves -> PV B-frags
    short8 pf[2][2];
#pragma unroll
    for (int ka = 0; ka < 2; ++ka) {
      {
        unsigned x0 = W0[2 * ka][0], y0 = W0[2 * ka + 1][0];
        unsigned x1 = W0[2 * ka][1], y1 = W0[2 * ka + 1][1];
        swap32(x0, y0);
        swap32(x1, y1);
        uint4v u = {x0, x1, y0, y1};
        pf[0][ka] = __builtin_bit_cast(short8, u);
      }
      {
        unsigned x0 = W1[2 * ka][0], y0 = W1[2 * ka + 1][0];
        unsigned x1 = W1[2 * ka][1], y1 = W1[2 * ka + 1][1];
        swap32(x0, y0);
        swap32(x1, y1);
        uint4v u = {x0, x1, y0, y1};
        pf[1][ka] = __builtin_bit_cast(short8, u);
      }
    }

    // ---- O^T += V^T x P^T
    __builtin_amdgcn_s_setprio(1);
#pragma unroll
    for (int sub = 0; sub < 2; ++sub)
#pragma unroll
      for (int ka = 0; ka < 2; ++ka) {
        const int un = ((sub * 4 + ka * 2 + l2h) ^ l7) * 8;
        const short8 va0 = *(const short8*)(VS + l31 * 64 + un);
        const short8 va1 = *(const short8*)(VS + (32 + l31) * 64 + un);
        OT0 = MFMA32(va0, pf[sub][ka], OT0);
        OT1 = MFMA32(va1, pf[sub][ka], OT1);
      }
    __builtin_amdgcn_s_setprio(0);

    if (more) {
      unsigned short* Kn = Ks[p ^ 1];
      unsigned short* Vn = Vs[p ^ 1];
      *(short8*)(Kn + sOffA) = k0;
      *(short8*)(Kn + sOffB) = k1;
      *(short8*)(Vn + sOffA) = v0;
      *(short8*)(Vn + sOffB) = v1;
    }
    __syncthreads();
    p ^= 1;
  }

  // ---- epilogue: bf16 un-normalized partials + (m, ls)
  unsigned short* Ob = (s == 0) ? Op0 : (OpR + (size_t)(s - 1) * Nseq * 1024);
  const int q = q0w + l31;
#pragma unroll
  for (int g = 0; g < 4; ++g) {
    const int d0 = 8 * g + 4 * l2h;
    uint2v t0 = {cvtpk(OT0[4 * g], OT0[4 * g + 1]), cvtpk(OT0[4 * g + 2], OT0[4 * g + 3])};
    uint2v t1 = {cvtpk(OT1[4 * g], OT1[4 * g + 1]), cvtpk(OT1[4 * g + 2], OT1[4 * g + 3])};
    *(uint2v*)(Ob + (size_t)q * 1024 + head * 64 + d0) = t0;
    *(uint2v*)(Ob + (size_t)q * 1024 + head * 64 + 32 + d0) = t1;
  }
  if (l2h == 0) {
    Ml[(size_t)(s * 16 + head) * Nseq + q] = m;
    Ll[(size_t)(s * 16 + head) * Nseq + q] = ls;
  }
}

// ---------------------------------------------------------------------------
// Combine the 4 key-split bf16 partials (exp2 domain) -> bf16 attention out.
// 8 elems/thread, grid 1024.
// ---------------------------------------------------------------------------
__global__ __launch_bounds__(256) void attn_combine4(const unsigned short* __restrict__ Op0,
                                                     const unsigned short* __restrict__ OpR,
                                                     const float* __restrict__ Ml,
                                                     const float* __restrict__ Ll,
                                                     unsigned short* __restrict__ out, int Nseq) {
  const int t = blockIdx.x * 256 + threadIdx.x;
  const int q = t >> 7, c8 = (t & 127) * 8;
  const int head = c8 >> 6;
  float mm[4], lv[4];
  float M = -1e30f;
#pragma unroll
  for (int s = 0; s < 4; ++s) {
    mm[s] = Ml[(size_t)(s * 16 + head) * Nseq + q];
    lv[s] = Ll[(size_t)(s * 16 + head) * Nseq + q];
    M = fmaxf(M, mm[s]);
  }
  float denom = 0.f;
  float acc[8] = {};
#pragma unroll
  for (int s = 0; s < 4; ++s) {
    const float ww = EXP2(mm[s] - M);
    denom += lv[s] * ww;
    const unsigned short* Ob = (s == 0) ? Op0 : (OpR + (size_t)(s - 1) * Nseq * 1024);
    uint4v o = *(const uint4v*)(Ob + (size_t)q * 1024 + c8);
    acc[0] += bflo(o.x) * ww; acc[1] += bfhi(o.x) * ww;
    acc[2] += bflo(o.y) * ww; acc[3] += bfhi(o.y) * ww;
    acc[4] += bflo(o.z) * ww; acc[5] += bfhi(o.z) * ww;
    acc[6] += bflo(o.w) * ww; acc[7] += bfhi(o.w) * ww;
  }
  const float inv = 1.f / denom;
  uint4v r;
  r.x = cvtpk(acc[0] * inv, acc[1] * inv);
  r.y = cvtpk(acc[2] * inv, acc[3] * inv);
  r.z = cvtpk(acc[4] * inv, acc[5] * inv);
  r.w = cvtpk(acc[6] * inv, acc[7] * inv);
  *(uint4v*)(out + (size_t)q * 1024 + c8) = r;
}

// ---------------------------------------------------------------------------
// Row LayerNorm (two-pass).  One block (256 thr) per row.
// IB: input is bf16 (otherwise fp32).  D==1024 vectorized 4/thread.
// ---------------------------------------------------------------------------
template <int D, bool IB, bool WF, bool WB>
__global__ __launch_bounds__(256) void ln_rows(const void* __restrict__ srcv,
                                               const float* __restrict__ gw,
                                               const float* __restrict__ bw,
                                               float* __restrict__ outF,
                                               unsigned short* __restrict__ outB) {
  __shared__ float red[4];
  const int row = blockIdx.x;
  const int tid = threadIdx.x, w = tid >> 6;
  if constexpr (D == 1024) {
    float vx, vy, vz, vw;
    if constexpr (IB) {
      const unsigned short* r = (const unsigned short*)srcv + (size_t)row * D;
      uint2v u = *(const uint2v*)(r + tid * 4);
      vx = bflo(u.x); vy = bfhi(u.x); vz = bflo(u.y); vw = bfhi(u.y);
    } else {
      const float* r = (const float*)srcv + (size_t)row * D;
      float4v v = ((const float4v*)r)[tid];
      vx = v.x; vy = v.y; vz = v.z; vw = v.w;
    }
    float s = (vx + vy) + (vz + vw);
#pragma unroll
    for (int off = 32; off; off >>= 1) s += __shfl_down(s, off);
    if ((tid & 63) == 0) red[w] = s;
    __syncthreads();
    const float mean = (red[0] + red[1] + red[2] + red[3]) / D;
    __syncthreads();
    const float dx = vx - mean, dy = vy - mean, dz = vz - mean, dw = vw - mean;
    float q = (dx * dx + dy * dy) + (dz * dz + dw * dw);
#pragma unroll
    for (int off = 32; off; off >>= 1) q += __shfl_down(q, off);
    if ((tid & 63) == 0) red[w] = q;
    __syncthreads();
    const float rstd = rsqrtf((red[0] + red[1] + red[2] + red[3]) / D + 1e-5f);
    float4v g4 = ((const float4v*)gw)[tid];
    float4v b4 = ((const float4v*)bw)[tid];
    float4v o;
    o.x = dx * rstd * g4.x + b4.x;
    o.y = dy * rstd * g4.y + b4.y;
    o.z = dz * rstd * g4.z + b4.z;
    o.w = dw * rstd * g4.w + b4.w;
    if constexpr (WF) ((float4v*)(outF + (size_t)row * D))[tid] = o;
    if constexpr (WB) {
      uint2v u = {cvtpk(o.x, o.y), cvtpk(o.z, o.w)};
      *(uint2v*)(outB + (size_t)row * D + tid * 4) = u;
    }
  } else {
    float v;
    if constexpr (IB) {
      v = bf2f(((const unsigned short*)srcv)[(size_t)row * D + tid]);
    } else {
      v = ((const float*)srcv)[(size_t)row * D + tid];
    }
    float s = v;
#pragma unroll
    for (int off = 32; off; off >>= 1) s += __shfl_down(s, off);
    if ((tid & 63) == 0) red[w] = s;
    __syncthreads();
    const float mean = (red[0] + red[1] + red[2] + red[3]) / D;
    __syncthreads();
    const float d = v - mean;
    float q = d * d;
#pragma unroll
    for (int off = 32; off; off >>= 1) q += __shfl_down(q, off);
    if ((tid & 63) == 0) red[w] = q;
    __syncthreads();
    const float rstd = rsqrtf((red[0] + red[1] + red[2] + red[3]) / D + 1e-5f);
    const float o = d * rstd * gw[tid] + bw[tid];
    if constexpr (WF) outF[(size_t)row * D + tid] = o;
    if constexpr (WB) outB[(size_t)row * D + tid] = f2bf(o);
  }
}

// ---------------------------------------------------------------------------
// Orchestration
// ---------------------------------------------------------------------------
extern "C" void kernel_launch(void* const* d_in, const int* in_sizes, int n_in,
                              void* d_out, int out_size, void* d_ws, size_t ws_size,
                              hipStream_t stream) {
  const int N = 2048, D_IN = 512, H = 1024, D_OUT = 256, NL = 4;
  const float* x    = (const float*)d_in[0];
  const float* W1   = (const float*)d_in[1];
  const float* b1   = (const float*)d_in[2];
  const float* Wqkv = (const float*)d_in[3];
  const float* bqkv = (const float*)d_in[4];
  const float* Wo   = (const float*)d_in[5];
  const float* bo   = (const float*)d_in[6];
  const float* lng  = (const float*)d_in[7];
  const float* lnb  = (const float*)d_in[8];
  const float* W2   = (const float*)d_in[9];
  const float* b2   = (const float*)d_in[10];
  const float* gout = (const float*)d_in[11];
  const float* bout = (const float*)d_in[12];
  float* out = (float*)d_out;

  char* ws = (char*)d_ws;
  auto alloc = [&](size_t bytes) -> char* {
    char* p = ws;
    ws += (bytes + 255) & ~(size_t)255;
    return p;
  };
  unsigned short* xb    = (unsigned short*)alloc((size_t)N * D_IN * 2);
  unsigned short* W1b   = (unsigned short*)alloc((size_t)H * D_IN * 2);
  unsigned short* Wqkvb = (unsigned short*)alloc((size_t)NL * 3 * H * H * 2);
  unsigned short* Wob   = (unsigned short*)alloc((size_t)NL * H * H * 2);
  unsigned short* W2b   = (unsigned short*)alloc((size_t)D_OUT * H * 2);
  unsigned short* hb    = (unsigned short*)alloc((size_t)N * H * 2);
  unsigned short* qkvb  = (unsigned short*)alloc((size_t)N * 3 * H * 2);
  unsigned short* aob   = (unsigned short*)alloc((size_t)N * H * 2);
  unsigned short* vtg   = (unsigned short*)alloc((size_t)H * N * 2);
  unsigned short* opb0  = (unsigned short*)alloc((size_t)N * H * 2);
  unsigned short* opbR  = (unsigned short*)alloc((size_t)3 * N * H * 2);
  unsigned short* afb   = (unsigned short*)alloc((size_t)N * H * 2);
  unsigned short* yfb   = (unsigned short*)alloc((size_t)N * D_OUT * 2);
  float* ml  = (float*)alloc((size_t)4 * 16 * N * 4);
  float* ll  = (float*)alloc((size_t)4 * 16 * N * 4);

  // ---- fused bf16 conversion (1 launch for all 5 arrays)
  CvtArgs ca;
  ca.s[0] = x;    ca.d[0] = xb;
  ca.s[1] = W1;   ca.d[1] = W1b;
  ca.s[2] = Wqkv; ca.d[2] = Wqkvb;
  ca.s[3] = Wo;   ca.d[3] = Wob;
  ca.s[4] = W2;   ca.d[4] = W2b;
  const int n0 = N * D_IN, n1 = H * D_IN, n2 = NL * 3 * H * H, n3 = NL * H * H, n4 = D_OUT * H;
  ca.off[0] = 0;
  ca.off[1] = n0;
  ca.off[2] = n0 + n1;
  ca.off[3] = n0 + n1 + n2;
  ca.off[4] = n0 + n1 + n2 + n3;
  ca.off[5] = n0 + n1 + n2 + n3 + n4;
  const int ntot4 = ca.off[5] / 4;
  cvt_multi<<<2048, 256, 0, stream>>>(ca, ntot4);

  // FC1: h = relu(x @ W1^T + b1) -> hb   (512 blocks, 2/CU)
  gemm_bt<64, 64, true, false, false, true, false><<<(N / 64) * (H / 64), 256, 0, stream>>>(
      xb, W1b, b1, nullptr, nullptr, hb, nullptr, 0, 0, N, H, D_IN);

  for (int l = 0; l < NL; ++l) {
    // qkv = h @ Wqkv^T + bqkv ; V^T into vtg; row-major writes only for Q,K
    // 64x128 tile -> 768 blocks (3/CU): block-level TLP hides barrier drains
    gemm_bt<64, 128, false, false, false, true, true><<<(N / 64) * (3 * H / 128), 256, 0, stream>>>(
        hb, Wqkvb + (size_t)l * 3 * H * H, bqkv + (size_t)l * 3 * H, nullptr, nullptr, qkvb,
        vtg, 2 * H, N, N, 3 * H, H);
    // flash attention -> bf16 partials
    flash_attn4<<<1024, 256, 0, stream>>>(qkvb, vtg, opb0, opbR, ml, ll, N);
    attn_combine4<<<1024, 256, 0, stream>>>(opb0, opbR, ml, ll, aob, N);
    // o-proj + bf16 residual -> afb (bf16)   (512 blocks, 2/CU)
    gemm_bt<64, 64, false, true, false, true, false><<<(N / 64) * (H / 64), 256, 0, stream>>>(
        aob, Wob + (size_t)l * H * H, bo + (size_t)l * H, hb, nullptr, afb, nullptr, 0, 0,
        N, H, H);
    // h = LN(afb) -> hb only
    ln_rows<1024, true, false, true><<<N, 256, 0, stream>>>(afb, lng + (size_t)l * H,
                                                            lnb + (size_t)l * H, nullptr, hb);
  }

  // FC2 (128 blocks of 64x64) -> yfb bf16
  gemm_bt<64, 64, true, false, false, true, false><<<(N / 64) * (D_OUT / 64), 256, 0, stream>>>(
      hb, W2b, b2, nullptr, nullptr, yfb, nullptr, 0, 0, N, D_OUT, H);
  ln_rows<256, true, true, false><<<N, 256, 0, stream>>>(yfb, gout, bout, out, nullptr);
}